// Round 2
// baseline (1784.916 us; speedup 1.0000x reference)
//
#include <hip/hip_runtime.h>
#include <hip/hip_bf16.h>
#include <math.h>

#define B_   4
#define T_   2048
#define V_   512
#define D_   256
#define H_   4
#define DH_  64
#define NB_  32
#define DFF_ 1024
#define NL_  2

// ---------------------------------------------------------------------------
// Kernel 1: token embedding gather + rank-2 delta projection
// one block per token, 256 threads (one per d)
// ---------------------------------------------------------------------------
__global__ __launch_bounds__(256) void embed_kernel(
    const int* __restrict__ tokens, const float* __restrict__ emb,
    const float* __restrict__ w_in, const float* __restrict__ w_out,
    float* __restrict__ x, float* __restrict__ delta)
{
    int bt = blockIdx.x;
    int d  = threadIdx.x;
    int tok = tokens[bt];
    float e = emb[tok * D_ + d];
    x[(long)bt * D_ + d] = e;

    __shared__ float r0s[256], r1s[256];
    r0s[d] = e * w_in[d * 2 + 0];
    r1s[d] = e * w_in[d * 2 + 1];
    __syncthreads();
    for (int off = 128; off > 0; off >>= 1) {
        if (d < off) { r0s[d] += r0s[d + off]; r1s[d] += r1s[d + off]; }
        __syncthreads();
    }
    float r0 = r0s[0], r1 = r1s[0];
    if (d < H_ * NB_) {  // 128 outputs
        delta[(long)bt * (H_ * NB_) + d] =
            r0 * w_out[d] + r1 * w_out[H_ * NB_ + d];
    }
}

// ---------------------------------------------------------------------------
// Kernel 2: cumsum over T per (b, channel) + cos/sin
// one block per (b, c) with c = h*NB+nb; 256 threads * 8 elems = 2048 = T
// ---------------------------------------------------------------------------
__global__ __launch_bounds__(256) void cumsum_kernel(
    const float* __restrict__ delta, const float* __restrict__ omega,
    float* __restrict__ cosb, float* __restrict__ sinb)
{
    int c = blockIdx.x & (H_ * NB_ - 1);
    int b = blockIdx.x >> 7;
    int tid = threadIdx.x;
    float om = omega[c];
    int h = c >> 5, nb = c & (NB_ - 1);

    float vals[8];
    float s = 0.0f;
    for (int i = 0; i < 8; ++i) {
        int t = tid * 8 + i;
        vals[i] = delta[((long)b * T_ + t) * (H_ * NB_) + c];
        s += vals[i];
    }
    __shared__ float sc[256];
    sc[tid] = s;
    __syncthreads();
    for (int off = 1; off < 256; off <<= 1) {
        float v = (tid >= off) ? sc[tid - off] : 0.0f;
        __syncthreads();
        sc[tid] += v;
        __syncthreads();
    }
    float run = sc[tid] - s;  // exclusive prefix
    for (int i = 0; i < 8; ++i) {
        run += vals[i];
        float ang = run * om;
        int t = tid * 8 + i;
        long oi = ((long)(b * H_ + h) * T_ + t) * NB_ + nb;
        cosb[oi] = cosf(ang);
        sinb[oi] = sinf(ang);
    }
}

// ---------------------------------------------------------------------------
// Kernel 3: LayerNorm, one block (256 threads) per row of D=256
// ---------------------------------------------------------------------------
__global__ __launch_bounds__(256) void ln_kernel(
    const float* __restrict__ x, const float* __restrict__ g,
    const float* __restrict__ b, float* __restrict__ out)
{
    int row = blockIdx.x;
    int d = threadIdx.x;
    float v = x[(long)row * D_ + d];
    __shared__ float ss[256], sq[256];
    ss[d] = v; sq[d] = v * v;
    __syncthreads();
    for (int off = 128; off > 0; off >>= 1) {
        if (d < off) { ss[d] += ss[d + off]; sq[d] += sq[d + off]; }
        __syncthreads();
    }
    float mu  = ss[0] * (1.0f / D_);
    float var = sq[0] * (1.0f / D_) - mu * mu;
    float inv = rsqrtf(var + 1e-5f);
    out[(long)row * D_ + d] = (v - mu) * inv * g[d] + b[d];
}

// ---------------------------------------------------------------------------
// Kernel 4: generic fp32 GEMM  C[M,N] = A[M,K] @ W[K,N] + bias (+res)(+gelu)
// BM=BN=64, BK=16, 256 threads, 4x4 outputs/thread.
// a_attn:   A is stored (B,H,T,DH), logical row=b*T+t, col k=h*DH+dh
// out_attn: write C to (B,H,T,DH) layout (N must be D_)
// ---------------------------------------------------------------------------
__global__ __launch_bounds__(256) void gemm_kernel(
    const float* __restrict__ A, const float* __restrict__ W,
    const float* __restrict__ bias, const float* res,
    float* outf,
    int M, int N, int K, int a_attn, int out_attn, int do_gelu)
{
    __shared__ float As[64][17];  // [row][k]
    __shared__ float Ws[16][65];  // [k][col]
    int tid = threadIdx.x;
    int tx = tid & 15, ty = tid >> 4;
    int r0 = blockIdx.y * 64, n0 = blockIdx.x * 64;

    float acc[4][4] = {};
    for (int k0 = 0; k0 < K; k0 += 16) {
        for (int l = 0; l < 4; ++l) {
            int e = tid + 256 * l;
            int r = e >> 4, kk = e & 15;
            int row = r0 + r, kg = k0 + kk;
            long idx;
            if (a_attn) {
                int b = row >> 11, t = row & (T_ - 1);
                idx = ((long)(b * H_ + (kg >> 6)) * T_ + t) * DH_ + (kg & 63);
            } else {
                idx = (long)row * K + kg;
            }
            As[r][kk] = A[idx];
        }
        for (int l = 0; l < 4; ++l) {
            int e = tid + 256 * l;
            int kk = e >> 6, c = e & 63;
            Ws[kk][c] = W[(long)(k0 + kk) * N + (n0 + c)];
        }
        __syncthreads();
#pragma unroll
        for (int kk = 0; kk < 16; ++kk) {
            float a[4], bv[4];
            for (int i = 0; i < 4; ++i) a[i]  = As[ty * 4 + i][kk];
            for (int j = 0; j < 4; ++j) bv[j] = Ws[kk][tx * 4 + j];
            for (int i = 0; i < 4; ++i)
                for (int j = 0; j < 4; ++j) acc[i][j] += a[i] * bv[j];
        }
        __syncthreads();
    }

    for (int i = 0; i < 4; ++i) {
        int row = r0 + ty * 4 + i;
        for (int j = 0; j < 4; ++j) {
            int n = n0 + tx * 4 + j;
            float v = acc[i][j] + bias[n];
            if (res) v += res[(long)row * N + n];
            if (do_gelu) v = 0.5f * v * (1.0f + erff(v * 0.70710678118654752f));
            if (out_attn) {
                int b = row >> 11, t = row & (T_ - 1);
                outf[((long)(b * H_ + (n >> 6)) * T_ + t) * DH_ + (n & 63)] = v;
            } else {
                outf[(long)row * N + n] = v;
            }
        }
    }
}

// ---------------------------------------------------------------------------
// Kernel 5: RoPE in-place on Q and K ((B,H,T,DH) layout); one thread per pair
// ---------------------------------------------------------------------------
__global__ __launch_bounds__(256) void rope_kernel(
    float* __restrict__ Q, float* __restrict__ Kb,
    const float* __restrict__ cosb, const float* __restrict__ sinb, int n)
{
    int i = blockIdx.x * blockDim.x + threadIdx.x;
    if (i >= n) return;
    float c = cosb[i], s = sinb[i];
    float q0 = Q[2 * i], q1 = Q[2 * i + 1];
    Q[2 * i]     = q0 * c - q1 * s;
    Q[2 * i + 1] = q0 * s + q1 * c;
    float k0 = Kb[2 * i], k1 = Kb[2 * i + 1];
    Kb[2 * i]     = k0 * c - k1 * s;
    Kb[2 * i + 1] = k0 * s + k1 * c;
}

// ---------------------------------------------------------------------------
// Kernel 6: flash-style causal attention.
// grid (T/64, B*H); block 256 = 16x16 threads, 4x4 outputs each.
// P tile aliases K's LDS (K reads all complete before P writes - barriers).
// O overwrites Q's buffer (each block writes only the Q rows it read).
// ---------------------------------------------------------------------------
__global__ __launch_bounds__(256) void attn_kernel(
    const float* __restrict__ Q, const float* __restrict__ K,
    const float* __restrict__ V, float* __restrict__ O)
{
    __shared__ float Qs[64][65];
    __shared__ float KPs[64][65];  // K tile, then reused for P tile
    __shared__ float Vs[64][65];
    __shared__ float red[16][64];
    __shared__ float rowm[64], rowl[64], rowa[64];

    int tid = threadIdx.x;
    int tx = tid & 15, ty = tid >> 4;
    int qt = blockIdx.x, bh = blockIdx.y;
    int q0 = qt * 64;
    const long base = (long)bh * T_ * DH_;

    for (int l = 0; l < 16; ++l) {
        int e = tid + 256 * l;
        int r = e >> 6, d = e & 63;
        Qs[r][d] = Q[base + (long)(q0 + r) * DH_ + d];
    }
    if (tid < 64) { rowm[tid] = -1e30f; rowl[tid] = 0.0f; }

    float o[4][4] = {};
    for (int kt = 0; kt <= qt; ++kt) {
        int k0 = kt * 64;
        __syncthreads();  // guard LDS reuse across iterations + init visibility
        for (int l = 0; l < 16; ++l) {
            int e = tid + 256 * l;
            int r = e >> 6, d = e & 63;
            KPs[r][d] = K[base + (long)(k0 + r) * DH_ + d];
            Vs[r][d]  = V[base + (long)(k0 + r) * DH_ + d];
        }
        __syncthreads();

        // S = Q K^T (this thread: rows ty*4+i, k-cols tx*4+j)
        float s[4][4] = {};
        for (int d = 0; d < 64; ++d) {
            float a[4], b[4];
            for (int i = 0; i < 4; ++i) a[i] = Qs[ty * 4 + i][d];
            for (int j = 0; j < 4; ++j) b[j] = KPs[tx * 4 + j][d];
            for (int i = 0; i < 4; ++i)
                for (int j = 0; j < 4; ++j) s[i][j] += a[i] * b[j];
        }
        // scale + causal mask + per-thread row max
        float pm[4];
        for (int i = 0; i < 4; ++i) {
            pm[i] = -1e30f;
            for (int j = 0; j < 4; ++j) {
                float sv = s[i][j] * 0.125f;  // 1/sqrt(64)
                if (k0 + tx * 4 + j > q0 + ty * 4 + i) sv = -1e30f;
                s[i][j] = sv;
                pm[i] = fmaxf(pm[i], sv);
            }
        }
        for (int i = 0; i < 4; ++i) red[tx][ty * 4 + i] = pm[i];
        __syncthreads();
        if (tid < 64) {
            float m = rowm[tid], mt = -1e30f;
            for (int t = 0; t < 16; ++t) mt = fmaxf(mt, red[t][tid]);
            float mn = fmaxf(m, mt);
            rowa[tid] = expf(m - mn);
            rowm[tid] = mn;
        }
        __syncthreads();
        // P = exp(S - m) ; write into K's LDS tile (safe: K reads done)
        float pl[4];
        for (int i = 0; i < 4; ++i) {
            float mn = rowm[ty * 4 + i];
            pl[i] = 0.0f;
            for (int j = 0; j < 4; ++j) {
                float p = expf(s[i][j] - mn);
                KPs[ty * 4 + i][tx * 4 + j] = p;
                pl[i] += p;
            }
        }
        for (int i = 0; i < 4; ++i) red[tx][ty * 4 + i] = pl[i];
        __syncthreads();
        if (tid < 64) {
            float sum = 0.0f;
            for (int t = 0; t < 16; ++t) sum += red[t][tid];
            rowl[tid] = rowl[tid] * rowa[tid] + sum;
        }
        // O = O*alpha + P @ V
        float al[4];
        for (int i = 0; i < 4; ++i) al[i] = rowa[ty * 4 + i];
        for (int i = 0; i < 4; ++i)
            for (int j = 0; j < 4; ++j) o[i][j] *= al[i];
        for (int d = 0; d < 64; ++d) {
            float p[4], vv[4];
            for (int i = 0; i < 4; ++i) p[i]  = KPs[ty * 4 + i][d];
            for (int j = 0; j < 4; ++j) vv[j] = Vs[d][tx * 4 + j];
            for (int i = 0; i < 4; ++i)
                for (int j = 0; j < 4; ++j) o[i][j] += p[i] * vv[j];
        }
    }
    __syncthreads();  // rowl final values visible
    for (int i = 0; i < 4; ++i) {
        float inv = 1.0f / rowl[ty * 4 + i];
        long orow = base + (long)(q0 + ty * 4 + i) * DH_;
        for (int j = 0; j < 4; ++j) O[orow + tx * 4 + j] = o[i][j] * inv;
    }
}

// ---------------------------------------------------------------------------
extern "C" void kernel_launch(void* const* d_in, const int* in_sizes, int n_in,
                              void* d_out, int out_size, void* d_ws, size_t ws_size,
                              hipStream_t stream)
{
    const int*   tokens    = (const int*)d_in[0];
    const float* token_emb = (const float*)d_in[1];
    const float* w_in      = (const float*)d_in[2];
    const float* w_out     = (const float*)d_in[3];
    const float* omega     = (const float*)d_in[4];
    const float* Wq        = (const float*)d_in[5];
    const float* bq        = (const float*)d_in[6];
    const float* Wk        = (const float*)d_in[7];
    const float* bk        = (const float*)d_in[8];
    const float* Wv        = (const float*)d_in[9];
    const float* bv        = (const float*)d_in[10];
    const float* Wo        = (const float*)d_in[11];
    const float* bo        = (const float*)d_in[12];
    const float* ln1_g     = (const float*)d_in[13];
    const float* ln1_b     = (const float*)d_in[14];
    const float* ln2_g     = (const float*)d_in[15];
    const float* ln2_b     = (const float*)d_in[16];
    const float* W1        = (const float*)d_in[17];
    const float* b1        = (const float*)d_in[18];
    const float* W2        = (const float*)d_in[19];
    const float* b2        = (const float*)d_in[20];
    const float* out_g     = (const float*)d_in[21];
    const float* out_b     = (const float*)d_in[22];
    const float* Wout      = (const float*)d_in[23];
    const float* bout      = (const float*)d_in[24];

    const size_t NTOK = (size_t)B_ * T_;  // 8192
    float* ws    = (float*)d_ws;
    float* xbuf  = ws;                       // 8192*256
    float* hbuf  = xbuf + NTOK * D_;         // 8192*256
    float* qbuf  = hbuf + NTOK * D_;         // 8192*256 (B,H,T,DH)
    float* kbuf  = qbuf + NTOK * D_;
    float* vbuf  = kbuf + NTOK * D_;
    float* ffbuf = vbuf + NTOK * D_;         // 8192*1024
    float* dbuf  = ffbuf;                    // aliases ffbuf (dead before FFN)
    float* cosb  = ffbuf + NTOK * DFF_;      // 1048576
    float* sinb  = cosb + NTOK * H_ * NB_;   // 1048576
    // total ~80 MB of workspace

    embed_kernel<<<NTOK, 256, 0, stream>>>(tokens, token_emb, w_in, w_out, xbuf, dbuf);
    cumsum_kernel<<<B_ * H_ * NB_, 256, 0, stream>>>(dbuf, omega, cosb, sinb);

    for (int l = 0; l < NL_; ++l) {
        ln_kernel<<<NTOK, 256, 0, stream>>>(xbuf, ln1_g + l * D_, ln1_b + l * D_, hbuf);
        gemm_kernel<<<dim3(D_ / 64, NTOK / 64), 256, 0, stream>>>(
            hbuf, Wq + (size_t)l * D_ * D_, bq + l * D_, nullptr, qbuf,
            (int)NTOK, D_, D_, 0, 1, 0);
        gemm_kernel<<<dim3(D_ / 64, NTOK / 64), 256, 0, stream>>>(
            hbuf, Wk + (size_t)l * D_ * D_, bk + l * D_, nullptr, kbuf,
            (int)NTOK, D_, D_, 0, 1, 0);
        gemm_kernel<<<dim3(D_ / 64, NTOK / 64), 256, 0, stream>>>(
            hbuf, Wv + (size_t)l * D_ * D_, bv + l * D_, nullptr, vbuf,
            (int)NTOK, D_, D_, 0, 1, 0);
        rope_kernel<<<(B_ * H_ * T_ * NB_ + 255) / 256, 256, 0, stream>>>(
            qbuf, kbuf, cosb, sinb, B_ * H_ * T_ * NB_);
        attn_kernel<<<dim3(T_ / 64, B_ * H_), 256, 0, stream>>>(qbuf, kbuf, vbuf, qbuf);
        gemm_kernel<<<dim3(D_ / 64, NTOK / 64), 256, 0, stream>>>(
            qbuf, Wo + (size_t)l * D_ * D_, bo + l * D_, xbuf, xbuf,
            (int)NTOK, D_, D_, 1, 0, 0);
        ln_kernel<<<NTOK, 256, 0, stream>>>(xbuf, ln2_g + l * D_, ln2_b + l * D_, hbuf);
        gemm_kernel<<<dim3(DFF_ / 64, NTOK / 64), 256, 0, stream>>>(
            hbuf, W1 + (size_t)l * D_ * DFF_, b1 + l * DFF_, nullptr, ffbuf,
            (int)NTOK, DFF_, D_, 0, 0, 1);
        gemm_kernel<<<dim3(D_ / 64, NTOK / 64), 256, 0, stream>>>(
            ffbuf, W2 + (size_t)l * DFF_ * D_, b2 + l * D_, xbuf, xbuf,
            (int)NTOK, D_, DFF_, 0, 0, 0);
    }

    ln_kernel<<<NTOK, 256, 0, stream>>>(xbuf, out_g, out_b, hbuf);
    gemm_kernel<<<dim3(V_ / 64, NTOK / 64), 256, 0, stream>>>(
        hbuf, Wout, bout, nullptr, (float*)d_out,
        (int)NTOK, V_, D_, 0, 0, 0);
}

// Round 3
// 550.785 us; speedup vs baseline: 3.2407x; 3.2407x over previous
//
#include <hip/hip_runtime.h>
#include <hip/hip_bf16.h>
#include <math.h>

#define B_   4
#define T_   2048
#define V_   512
#define D_   256
#define H_   4
#define DH_  64
#define NB_  32
#define DFF_ 1024
#define NL_  2

typedef __attribute__((ext_vector_type(8))) short short8_t;
typedef __attribute__((ext_vector_type(4))) float float4_t;

#define MFMA16(a,b,c) __builtin_amdgcn_mfma_f32_16x16x32_bf16(a,b,c,0,0,0)

__device__ __forceinline__ unsigned short f2bf_bits(float f) {
    unsigned u = __float_as_uint(f);
    u += 0x7fffu + ((u >> 16) & 1u);
    return (unsigned short)(u >> 16);
}

// ---------------------------------------------------------------------------
// Weight transpose+cast: W[K][N] fp32 -> Wt[N][K] bf16. One 32x32 tile/block.
// ---------------------------------------------------------------------------
__global__ __launch_bounds__(256) void wt_kernel(
    const float* __restrict__ Wq, const float* __restrict__ Wk,
    const float* __restrict__ Wv, const float* __restrict__ Wo,
    const float* __restrict__ W1, const float* __restrict__ W2,
    const float* __restrict__ Wout,
    unsigned short* __restrict__ wqt, unsigned short* __restrict__ wkt,
    unsigned short* __restrict__ wvt, unsigned short* __restrict__ wot,
    unsigned short* __restrict__ w1t, unsigned short* __restrict__ w2t,
    unsigned short* __restrict__ woutt)
{
    __shared__ float tile[32][33];
    int bx = blockIdx.x, tid = threadIdx.x;
    const float* src; unsigned short* dst; int Kd, Nd, tr, tc;
    if (bx < 512) {                    // Wq/Wk/Wv/Wo, 2 layers each, 256x256
        int am = bx >> 6, t = bx & 63;
        const float* s4[4] = {Wq, Wk, Wv, Wo};
        unsigned short* d4[4] = {wqt, wkt, wvt, wot};
        src = s4[am >> 1] + (long)(am & 1) * 65536;
        dst = d4[am >> 1] + (long)(am & 1) * 65536;
        Kd = 256; Nd = 256; tr = t >> 3; tc = t & 7;
    } else if (bx < 1024) {            // W1: 2 x (256x1024)
        int idx = bx - 512, mat = idx >> 8, t = idx & 255;
        src = W1 + (long)mat * 262144; dst = w1t + (long)mat * 262144;
        Kd = 256; Nd = 1024; tr = t >> 5; tc = t & 31;
    } else if (bx < 1536) {            // W2: 2 x (1024x256)
        int idx = bx - 1024, mat = idx >> 8, t = idx & 255;
        src = W2 + (long)mat * 262144; dst = w2t + (long)mat * 262144;
        Kd = 1024; Nd = 256; tr = t >> 3; tc = t & 7;
    } else {                           // Wout: 256x512
        int t = bx - 1536;
        src = Wout; dst = woutt; Kd = 256; Nd = 512; tr = t >> 4; tc = t & 15;
    }
    int kr = tid >> 3, nc4 = (tid & 7) * 4;
    float4_t v = *(const float4_t*)&src[(long)(tr * 32 + kr) * Nd + tc * 32 + nc4];
    for (int j = 0; j < 4; ++j) tile[kr][nc4 + j] = v[j];
    __syncthreads();
    int nr = tid >> 3, kc4 = (tid & 7) * 4;
    unsigned short tmp[4];
    for (int j = 0; j < 4; ++j) tmp[j] = f2bf_bits(tile[kc4 + j][nr]);
    uint2 uu;
    uu.x = (unsigned)tmp[0] | ((unsigned)tmp[1] << 16);
    uu.y = (unsigned)tmp[2] | ((unsigned)tmp[3] << 16);
    *(uint2*)&dst[(long)(tc * 32 + nr) * Kd + tr * 32 + kc4] = uu;
}

// ---------------------------------------------------------------------------
// Token embedding gather + rank-2 delta projection
// ---------------------------------------------------------------------------
__global__ __launch_bounds__(256) void embed_kernel(
    const int* __restrict__ tokens, const float* __restrict__ emb,
    const float* __restrict__ w_in, const float* __restrict__ w_out,
    float* __restrict__ x, float* __restrict__ delta)
{
    int bt = blockIdx.x;
    int d  = threadIdx.x;
    int tok = tokens[bt];
    float e = emb[tok * D_ + d];
    x[(long)bt * D_ + d] = e;

    __shared__ float r0s[256], r1s[256];
    r0s[d] = e * w_in[d * 2 + 0];
    r1s[d] = e * w_in[d * 2 + 1];
    __syncthreads();
    for (int off = 128; off > 0; off >>= 1) {
        if (d < off) { r0s[d] += r0s[d + off]; r1s[d] += r1s[d + off]; }
        __syncthreads();
    }
    float r0 = r0s[0], r1 = r1s[0];
    if (d < H_ * NB_) {
        delta[(long)bt * (H_ * NB_) + d] =
            r0 * w_out[d] + r1 * w_out[H_ * NB_ + d];
    }
}

// ---------------------------------------------------------------------------
// cumsum over T per (b, channel) + cos/sin
// ---------------------------------------------------------------------------
__global__ __launch_bounds__(256) void cumsum_kernel(
    const float* __restrict__ delta, const float* __restrict__ omega,
    float* __restrict__ cosb, float* __restrict__ sinb)
{
    int c = blockIdx.x & (H_ * NB_ - 1);
    int b = blockIdx.x >> 7;
    int tid = threadIdx.x;
    float om = omega[c];
    int h = c >> 5, nb = c & (NB_ - 1);

    float vals[8];
    float s = 0.0f;
    for (int i = 0; i < 8; ++i) {
        int t = tid * 8 + i;
        vals[i] = delta[((long)b * T_ + t) * (H_ * NB_) + c];
        s += vals[i];
    }
    __shared__ float sc[256];
    sc[tid] = s;
    __syncthreads();
    for (int off = 1; off < 256; off <<= 1) {
        float v = (tid >= off) ? sc[tid - off] : 0.0f;
        __syncthreads();
        sc[tid] += v;
        __syncthreads();
    }
    float run = sc[tid] - s;
    for (int i = 0; i < 8; ++i) {
        run += vals[i];
        float ang = run * om;
        int t = tid * 8 + i;
        long oi = ((long)(b * H_ + h) * T_ + t) * NB_ + nb;
        cosb[oi] = cosf(ang);
        sinb[oi] = sinf(ang);
    }
}

// ---------------------------------------------------------------------------
// LayerNorm (fp32 in) -> bf16 out
// ---------------------------------------------------------------------------
__global__ __launch_bounds__(256) void ln_kernel(
    const float* __restrict__ x, const float* __restrict__ g,
    const float* __restrict__ b, unsigned short* __restrict__ out)
{
    int row = blockIdx.x;
    int d = threadIdx.x;
    float v = x[(long)row * D_ + d];
    __shared__ float ss[256], sq[256];
    ss[d] = v; sq[d] = v * v;
    __syncthreads();
    for (int off = 128; off > 0; off >>= 1) {
        if (d < off) { ss[d] += ss[d + off]; sq[d] += sq[d + off]; }
        __syncthreads();
    }
    float mu  = ss[0] * (1.0f / D_);
    float var = sq[0] * (1.0f / D_) - mu * mu;
    float inv = rsqrtf(var + 1e-5f);
    out[(long)row * D_ + d] = f2bf_bits((v - mu) * inv * g[d] + b[d]);
}

// ---------------------------------------------------------------------------
// MFMA GEMM: C[M,N] = A[M,K](bf16) @ Bt[N,K](bf16)^T + bias, optional
// residual add (fp32, N==256), gelu, and output layout variants.
// 64x64 tile, BK=64, 4 waves x (16x64 strip), 16x16x32 MFMA.
// ---------------------------------------------------------------------------
__global__ __launch_bounds__(256) void gemm_mfma(
    const unsigned short* __restrict__ A, const unsigned short* __restrict__ Bt,
    const float* __restrict__ bias, const float* __restrict__ res,
    float* __restrict__ outf, unsigned short* __restrict__ outb,
    int M, int N, int K, int out_attn, int do_gelu)
{
    __shared__ __align__(16) short As[64 * 72];
    __shared__ __align__(16) short Bs[64 * 72];
    int tid = threadIdx.x;
    int w = tid >> 6, lane = tid & 63, quad = lane >> 4, l16 = lane & 15;
    int n0 = blockIdx.x * 64, r0 = blockIdx.y * 64;

    float4_t acc[4];
    for (int nt = 0; nt < 4; ++nt) acc[nt] = (float4_t){0.f, 0.f, 0.f, 0.f};

    for (int k0 = 0; k0 < K; k0 += 64) {
        __syncthreads();
        for (int i = 0; i < 2; ++i) {
            int e = tid + 256 * i;
            int r = e >> 3, c8 = e & 7;
            *(short8_t*)&As[r * 72 + c8 * 8] =
                *(const short8_t*)&A[(long)(r0 + r) * K + k0 + c8 * 8];
            *(short8_t*)&Bs[r * 72 + c8 * 8] =
                *(const short8_t*)&Bt[(long)(n0 + r) * K + k0 + c8 * 8];
        }
        __syncthreads();
        for (int kq = 0; kq < 2; ++kq) {
            short8_t a = *(const short8_t*)&As[(w * 16 + l16) * 72 + kq * 32 + quad * 8];
            for (int nt = 0; nt < 4; ++nt) {
                short8_t bfr = *(const short8_t*)&Bs[(nt * 16 + l16) * 72 + kq * 32 + quad * 8];
                acc[nt] = MFMA16(a, bfr, acc[nt]);
            }
        }
    }

    for (int nt = 0; nt < 4; ++nt) {
        int n = n0 + nt * 16 + l16;
        float bv = bias[n];
        for (int r = 0; r < 4; ++r) {
            int row = r0 + w * 16 + quad * 4 + r;
            float v = acc[nt][r] + bv;
            if (res) v += res[(long)row * N + n];
            if (do_gelu) v = 0.5f * v * (1.0f + erff(v * 0.70710678118654752f));
            if (out_attn) {
                int bb = row >> 11, t = row & (T_ - 1);
                outf[((long)(bb * H_ + (n >> 6)) * T_ + t) * DH_ + (n & 63)] = v;
            } else if (outb) {
                outb[(long)row * N + n] = f2bf_bits(v);
            } else {
                outf[(long)row * N + n] = v;
            }
        }
    }
}

// ---------------------------------------------------------------------------
// RoPE in-place on Q and K ((B,H,T,DH) fp32)
// ---------------------------------------------------------------------------
__global__ __launch_bounds__(256) void rope_kernel(
    float* __restrict__ Q, float* __restrict__ Kb,
    const float* __restrict__ cosb, const float* __restrict__ sinb, int n)
{
    int i = blockIdx.x * blockDim.x + threadIdx.x;
    if (i >= n) return;
    float c = cosb[i], s = sinb[i];
    float q0 = Q[2 * i], q1 = Q[2 * i + 1];
    Q[2 * i]     = q0 * c - q1 * s;
    Q[2 * i + 1] = q0 * s + q1 * c;
    float k0 = Kb[2 * i], k1 = Kb[2 * i + 1];
    Kb[2 * i]     = k0 * c - k1 * s;
    Kb[2 * i + 1] = k0 * s + k1 * c;
}

// ---------------------------------------------------------------------------
// MFMA flash attention. Block = 4 waves, 64 Q rows per block (16/wave).
// Q in A-frags (regs), K staged to LDS bf16, V B-frags direct from global.
// Softmax in-register on C-layout (row=quad*4+reg, col=lane&15), stats via
// 16-lane xor shuffles. P -> wave-private LDS strip -> A-frags (no barrier).
// O written bf16 to obuf[8192][256] row-major.
// ---------------------------------------------------------------------------
__global__ __launch_bounds__(256) void attn_mfma(
    const float* __restrict__ Q, const float* __restrict__ K,
    const float* __restrict__ V, unsigned short* __restrict__ O)
{
    __shared__ __align__(16) short Ks[64 * 72];
    __shared__ __align__(16) short Ps[4][16 * 72];

    int tid = threadIdx.x;
    int w = tid >> 6, lane = tid & 63;
    int quad = lane >> 4, l16 = lane & 15;
    int bh = blockIdx.x & 15;
    int qi = blockIdx.x >> 4;
    int qt = (qi < 16) ? qi : 47 - qi;   // pair qt with 31-qt for CU balance
    int q0 = qt * 64;
    const long base = (long)bh * T_ * DH_;

    // Q A-frags, held all kernel
    short8_t aq[2];
    {
        int qrow = q0 + w * 16 + l16;
        const float* qp = Q + base + (long)qrow * DH_ + quad * 8;
        for (int kq = 0; kq < 2; ++kq) {
            float4_t f0 = *(const float4_t*)(qp + kq * 32);
            float4_t f1 = *(const float4_t*)(qp + kq * 32 + 4);
            for (int j = 0; j < 4; ++j) {
                aq[kq][j]     = (short)f2bf_bits(f0[j]);
                aq[kq][4 + j] = (short)f2bf_bits(f1[j]);
            }
        }
    }

    float m_r[4], l_r[4];
    for (int r = 0; r < 4; ++r) { m_r[r] = -3.0e38f; l_r[r] = 0.0f; }
    float4_t o[4];
    for (int nt = 0; nt < 4; ++nt) o[nt] = (float4_t){0.f, 0.f, 0.f, 0.f};

    for (int kt = 0; kt <= qt; ++kt) {
        int k0 = kt * 64;
        __syncthreads();   // protect Ks reuse
        for (int i = 0; i < 2; ++i) {
            int e = tid + 256 * i;
            int r = e >> 3, c8 = e & 7;
            const float* kp = K + base + (long)(k0 + r) * DH_ + c8 * 8;
            float4_t f0 = *(const float4_t*)kp;
            float4_t f1 = *(const float4_t*)(kp + 4);
            short8_t kv;
            for (int j = 0; j < 4; ++j) {
                kv[j]     = (short)f2bf_bits(f0[j]);
                kv[4 + j] = (short)f2bf_bits(f1[j]);
            }
            *(short8_t*)&Ks[r * 72 + c8 * 8] = kv;
        }
        __syncthreads();

        // V B-frags straight from global (L2-resident)
        short8_t vb[4][2];
        for (int nt = 0; nt < 4; ++nt) {
            int d = nt * 16 + l16;
            for (int kq = 0; kq < 2; ++kq) {
                const float* vp = V + base + (long)(k0 + kq * 32 + quad * 8) * DH_ + d;
                for (int j = 0; j < 8; ++j)
                    vb[nt][kq][j] = (short)f2bf_bits(vp[(long)j * DH_]);
            }
        }

        // S = Q K^T
        float4_t s[4];
        for (int nt = 0; nt < 4; ++nt) {
            s[nt] = (float4_t){0.f, 0.f, 0.f, 0.f};
            for (int kq = 0; kq < 2; ++kq) {
                short8_t kb = *(const short8_t*)&Ks[(nt * 16 + l16) * 72 + kq * 32 + quad * 8];
                s[nt] = MFMA16(aq[kq], kb, s[nt]);
            }
        }

        // scale + causal mask + row max (C layout: row=quad*4+r, col=l16)
        bool diag = (kt == qt);
        float mt[4];
        for (int r = 0; r < 4; ++r) mt[r] = -3.0e38f;
        for (int nt = 0; nt < 4; ++nt) {
            int kcol = k0 + nt * 16 + l16;
            for (int r = 0; r < 4; ++r) {
                float sv = s[nt][r] * 0.125f;
                if (diag && kcol > q0 + w * 16 + quad * 4 + r) sv = -3.0e38f;
                s[nt][r] = sv;
                mt[r] = fmaxf(mt[r], sv);
            }
        }
        for (int off = 1; off < 16; off <<= 1)
            for (int r = 0; r < 4; ++r)
                mt[r] = fmaxf(mt[r], __shfl_xor(mt[r], off));

        float alpha[4];
        for (int r = 0; r < 4; ++r) {
            float mn = fmaxf(m_r[r], mt[r]);
            alpha[r] = __expf(m_r[r] - mn);
            m_r[r] = mn;
        }

        float lt[4] = {0.f, 0.f, 0.f, 0.f};
        for (int nt = 0; nt < 4; ++nt) {
            for (int r = 0; r < 4; ++r) {
                float p = __expf(s[nt][r] - m_r[r]);
                lt[r] += p;
                Ps[w][(quad * 4 + r) * 72 + nt * 16 + l16] = (short)f2bf_bits(p);
            }
        }
        for (int off = 1; off < 16; off <<= 1)
            for (int r = 0; r < 4; ++r)
                lt[r] += __shfl_xor(lt[r], off);
        for (int r = 0; r < 4; ++r) l_r[r] = l_r[r] * alpha[r] + lt[r];
        for (int nt = 0; nt < 4; ++nt)
            for (int r = 0; r < 4; ++r) o[nt][r] *= alpha[r];

        // O += P @ V  (wave-private P strip, no barrier needed)
        for (int kq = 0; kq < 2; ++kq) {
            short8_t pa = *(const short8_t*)&Ps[w][l16 * 72 + kq * 32 + quad * 8];
            for (int nt = 0; nt < 4; ++nt)
                o[nt] = MFMA16(pa, vb[nt][kq], o[nt]);
        }
    }

    int b = bh >> 2, h = bh & 3;
    for (int r = 0; r < 4; ++r) {
        float inv = 1.0f / l_r[r];
        int trow = q0 + w * 16 + quad * 4 + r;
        long orow = ((long)b * T_ + trow) * D_ + h * 64;
        for (int nt = 0; nt < 4; ++nt)
            O[orow + nt * 16 + l16] = f2bf_bits(o[nt][r] * inv);
    }
}

// ---------------------------------------------------------------------------
extern "C" void kernel_launch(void* const* d_in, const int* in_sizes, int n_in,
                              void* d_out, int out_size, void* d_ws, size_t ws_size,
                              hipStream_t stream)
{
    const int*   tokens    = (const int*)d_in[0];
    const float* token_emb = (const float*)d_in[1];
    const float* w_in      = (const float*)d_in[2];
    const float* w_out     = (const float*)d_in[3];
    const float* omega     = (const float*)d_in[4];
    const float* Wq        = (const float*)d_in[5];
    const float* bq        = (const float*)d_in[6];
    const float* Wk        = (const float*)d_in[7];
    const float* bk        = (const float*)d_in[8];
    const float* Wv        = (const float*)d_in[9];
    const float* bv        = (const float*)d_in[10];
    const float* Wo        = (const float*)d_in[11];
    const float* bo        = (const float*)d_in[12];
    const float* ln1_g     = (const float*)d_in[13];
    const float* ln1_b     = (const float*)d_in[14];
    const float* ln2_g     = (const float*)d_in[15];
    const float* ln2_b     = (const float*)d_in[16];
    const float* W1        = (const float*)d_in[17];
    const float* b1        = (const float*)d_in[18];
    const float* W2        = (const float*)d_in[19];
    const float* b2        = (const float*)d_in[20];
    const float* out_g     = (const float*)d_in[21];
    const float* out_b     = (const float*)d_in[22];
    const float* Wout      = (const float*)d_in[23];
    const float* bout      = (const float*)d_in[24];

    const long NTOK = (long)B_ * T_;  // 8192
    float* xbuf = (float*)d_ws;                       // fp32 residual stream
    float* qbuf = xbuf + NTOK * D_;                   // (B,H,T,DH) fp32
    float* kbuf = qbuf + NTOK * D_;
    float* vbuf = kbuf + NTOK * D_;
    float* cosb = vbuf + NTOK * D_;                   // (B,H,T,NB) fp32
    float* sinb = cosb + NTOK * H_ * NB_;
    float* dbuf = sinb + NTOK * H_ * NB_;             // (B,T,H*NB) fp32
    unsigned short* hbuf  = (unsigned short*)(dbuf + NTOK * H_ * NB_); // bf16 LN out
    unsigned short* obuf  = hbuf + NTOK * D_;         // bf16 attn out
    unsigned short* ffbuf = obuf + NTOK * D_;         // bf16 FFN mid
    unsigned short* wqt   = ffbuf + NTOK * DFF_;      // transposed bf16 weights
    unsigned short* wkt   = wqt + 2 * 65536;
    unsigned short* wvt   = wkt + 2 * 65536;
    unsigned short* wot   = wvt + 2 * 65536;
    unsigned short* w1t   = wot + 2 * 65536;
    unsigned short* w2t   = w1t + 2 * 262144;
    unsigned short* woutt = w2t + 2 * 262144;
    // total ~75 MB

    wt_kernel<<<1664, 256, 0, stream>>>(Wq, Wk, Wv, Wo, W1, W2, Wout,
                                        wqt, wkt, wvt, wot, w1t, w2t, woutt);
    embed_kernel<<<NTOK, 256, 0, stream>>>(tokens, token_emb, w_in, w_out, xbuf, dbuf);
    cumsum_kernel<<<B_ * H_ * NB_, 256, 0, stream>>>(dbuf, omega, cosb, sinb);

    for (int l = 0; l < NL_; ++l) {
        ln_kernel<<<NTOK, 256, 0, stream>>>(xbuf, ln1_g + l * D_, ln1_b + l * D_, hbuf);
        gemm_mfma<<<dim3(4, 128), 256, 0, stream>>>(
            hbuf, wqt + (long)l * 65536, bq + l * D_, nullptr, qbuf, nullptr,
            (int)NTOK, D_, D_, 1, 0);
        gemm_mfma<<<dim3(4, 128), 256, 0, stream>>>(
            hbuf, wkt + (long)l * 65536, bk + l * D_, nullptr, kbuf, nullptr,
            (int)NTOK, D_, D_, 1, 0);
        gemm_mfma<<<dim3(4, 128), 256, 0, stream>>>(
            hbuf, wvt + (long)l * 65536, bv + l * D_, nullptr, vbuf, nullptr,
            (int)NTOK, D_, D_, 1, 0);
        rope_kernel<<<(B_ * H_ * T_ * NB_ + 255) / 256, 256, 0, stream>>>(
            qbuf, kbuf, cosb, sinb, B_ * H_ * T_ * NB_);
        attn_mfma<<<512, 256, 0, stream>>>(qbuf, kbuf, vbuf, obuf);
        gemm_mfma<<<dim3(4, 128), 256, 0, stream>>>(
            obuf, wot + (long)l * 65536, bo + l * D_, xbuf, xbuf, nullptr,
            (int)NTOK, D_, D_, 0, 0);
        ln_kernel<<<NTOK, 256, 0, stream>>>(xbuf, ln2_g + l * D_, ln2_b + l * D_, hbuf);
        gemm_mfma<<<dim3(16, 128), 256, 0, stream>>>(
            hbuf, w1t + (long)l * 262144, b1 + l * DFF_, nullptr, nullptr, ffbuf,
            (int)NTOK, DFF_, D_, 0, 1);
        gemm_mfma<<<dim3(4, 128), 256, 0, stream>>>(
            ffbuf, w2t + (long)l * 262144, b2 + l * D_, xbuf, xbuf, nullptr,
            (int)NTOK, D_, DFF_, 0, 0);
    }

    ln_kernel<<<NTOK, 256, 0, stream>>>(xbuf, out_g, out_b, hbuf);
    gemm_mfma<<<dim3(8, 128), 256, 0, stream>>>(
        hbuf, woutt, bout, nullptr, (float*)d_out, nullptr,
        (int)NTOK, V_, D_, 0, 0);
}